// Round 1
// baseline (385.279 us; speedup 1.0000x reference)
//
#include <hip/hip_runtime.h>
#include <hip/hip_cooperative_groups.h>

namespace cg = cooperative_groups;

#define GRID3 32768  // 32^3
#define FDIM 64
#define NBLOCKS 1024
#define NTHREADS 256
#define MMBLOCKS 512  // blocks that also produce min/max partials

// Single fused kernel: [zero output + minmax partials] -> grid.sync ->
// [reduce partials per-wave] -> [persistent-wave scatter-max].
__global__ __launch_bounds__(NTHREADS, 4)
void fused_gridpool(const float* __restrict__ pts,
                    const float* __restrict__ feat,
                    unsigned int* __restrict__ out,
                    float2* __restrict__ partials,
                    int npts_floats,  // B*N*3
                    int ntot,         // B*N
                    int N,
                    int out_floats)   // B*GRID3*FDIM
{
    const int tid = threadIdx.x;
    const int bid = blockIdx.x;
    __shared__ float smin[NTHREADS];
    __shared__ float smax[NTHREADS];

    // ---- Phase A1: zero the output grid (all blocks, float4 stores) ----
    {
        const float4 z = make_float4(0.f, 0.f, 0.f, 0.f);
        float4* o4 = reinterpret_cast<float4*>(out);
        const int n4 = out_floats >> 2;  // exact: out_floats % 4 == 0
        for (int i = bid * NTHREADS + tid; i < n4; i += NBLOCKS * NTHREADS)
            o4[i] = z;
    }

    // ---- Phase A2: per-block min/max partials (first MMBLOCKS blocks) ----
    if (bid < MMBLOCKS) {
        float lmin = INFINITY, lmax = -INFINITY;
        const float4* p4 = reinterpret_cast<const float4*>(pts);
        const int n4 = npts_floats >> 2;
        for (int i = bid * NTHREADS + tid; i < n4; i += MMBLOCKS * NTHREADS) {
            float4 v = p4[i];
            lmin = fminf(lmin, fminf(fminf(v.x, v.y), fminf(v.z, v.w)));
            lmax = fmaxf(lmax, fmaxf(fmaxf(v.x, v.y), fmaxf(v.z, v.w)));
        }
        // generic tail (empty when npts_floats % 4 == 0)
        for (int i = (n4 << 2) + bid * NTHREADS + tid; i < npts_floats;
             i += MMBLOCKS * NTHREADS) {
            float v = pts[i];
            lmin = fminf(lmin, v);
            lmax = fmaxf(lmax, v);
        }
        smin[tid] = lmin;
        smax[tid] = lmax;
        __syncthreads();
        for (int s = NTHREADS / 2; s > 0; s >>= 1) {
            if (tid < s) {
                smin[tid] = fminf(smin[tid], smin[tid + s]);
                smax[tid] = fmaxf(smax[tid], smax[tid + s]);
            }
            __syncthreads();
        }
        if (tid == 0) partials[bid] = make_float2(smin[0], smax[0]);
    }

    // One grid-wide barrier covers both deps: zero->atomics, partials->reduce.
    cg::this_grid().sync();

    // ---- Phase B: every wave redundantly reduces the 512 partials ----
    const int lane = tid & 63;
    float rmin = INFINITY, rmax = -INFINITY;
#pragma unroll
    for (int j = 0; j < MMBLOCKS / 64; ++j) {
        float2 v = partials[lane + 64 * j];
        rmin = fminf(rmin, v.x);
        rmax = fmaxf(rmax, v.y);
    }
#pragma unroll
    for (int s = 32; s > 0; s >>= 1) {
        rmin = fminf(rmin, __shfl_xor(rmin, s, 64));
        rmax = fmaxf(rmax, __shfl_xor(rmax, s, 64));
    }
    const float pmin = rmin;
    const float denom = rmax - rmin + 1e-6f;  // exact reference op order

    // ---- Phase C: persistent-wave scatter-max, contiguous chunk per wave ----
    const int nwaves = NBLOCKS * (NTHREADS / 64);
    const int wid = bid * (NTHREADS / 64) + (tid >> 6);
    const int cnt = (ntot + nwaves - 1) / nwaves;
    const int p0 = wid * cnt;
    const int p1 = min(ntot, p0 + cnt);
    if (p0 >= p1) return;  // safe: after the grid sync

    int b = p0 / N;                 // one integer div per wave, not per point
    int nextB = (b + 1) * N;
    const float* pp = pts + (size_t)p0 * 3;          // wave-uniform broadcast loads
    const float* fp = feat + (size_t)p0 * FDIM + lane;  // coalesced 256B rows
    unsigned int* ob = out + (size_t)b * GRID3 * FDIM + lane;

#pragma unroll 2
    for (int p = p0; p < p1; ++p) {
        if (p >= nextB) { ++b; nextB += N; ob += (size_t)GRID3 * FDIM; }
        const float x = pp[0];
        const float y = pp[1];
        const float zc = pp[2];
        pp += 3;
        const float f = fp[0];
        fp += FDIM;
        // Reference op order exactly: ((v - pmin) / denom) * 32, floor.
        // Values are >= 0, so int-trunc == floor.
        int vx = (int)(((x - pmin) / denom) * 32.0f);
        int vy = (int)(((y - pmin) / denom) * 32.0f);
        int vz = (int)(((zc - pmin) / denom) * 32.0f);
        vx = min(max(vx, 0), 31);
        vy = min(max(vy, 0), 31);
        vz = min(max(vz, 0), 31);
        const int gidx = (vx << 10) + (vy << 5) + vz;
        // Grid starts at 0; reference maxes against 0 => negative f never wins.
        // Positive IEEE floats order identically to their uint bit patterns.
        if (f > 0.0f)
            atomicMax(ob + (size_t)gidx * FDIM, __float_as_uint(f));
    }
}

extern "C" void kernel_launch(void* const* d_in, const int* in_sizes, int n_in,
                              void* d_out, int out_size, void* d_ws, size_t ws_size,
                              hipStream_t stream) {
    const float* pts = (const float*)d_in[0];
    const float* feat = (const float*)d_in[1];
    unsigned int* out = (unsigned int*)d_out;
    float2* partials = (float2*)d_ws;  // 512 * 8B = 4KB

    int npts3 = in_sizes[0];               // B*N*3
    int ntot = npts3 / 3;                  // B*N
    int B = out_size / (GRID3 * FDIM);
    int N = ntot / B;
    int out_floats = out_size;

    void* args[] = {(void*)&pts, (void*)&feat, (void*)&out, (void*)&partials,
                    (void*)&npts3, (void*)&ntot, (void*)&N, (void*)&out_floats};
    hipLaunchCooperativeKernel((const void*)fused_gridpool, dim3(NBLOCKS),
                               dim3(NTHREADS), args, 0, stream);
}

// Round 2
// 347.631 us; speedup vs baseline: 1.1083x; 1.1083x over previous
//
#include <hip/hip_runtime.h>

#define GRID3 32768  // 32^3
#define FDIM 64

// Order-preserving float<->uint encoding (monotonic: enc(a)<enc(b) iff a<b)
__device__ __forceinline__ unsigned int enc_f32(float f) {
    unsigned int u = __float_as_uint(f);
    return (u & 0x80000000u) ? ~u : (u | 0x80000000u);
}
__device__ __forceinline__ float dec_f32(unsigned int u) {
    u = (u & 0x80000000u) ? (u ^ 0x80000000u) : ~u;
    return __uint_as_float(u);
}

__global__ void init_ws_kernel(unsigned int* ws) {
    ws[0] = 0xFFFFFFFFu;  // encoded min accumulator
    ws[1] = 0u;           // encoded max accumulator
}

__global__ void minmax_kernel(const float* __restrict__ pts, int n,
                              unsigned int* __restrict__ ws) {
    float lmin = INFINITY, lmax = -INFINITY;
    const float4* p4 = reinterpret_cast<const float4*>(pts);
    const int n4 = n >> 2;
    for (int i = blockIdx.x * blockDim.x + threadIdx.x; i < n4;
         i += gridDim.x * blockDim.x) {
        float4 v = p4[i];
        lmin = fminf(lmin, fminf(fminf(v.x, v.y), fminf(v.z, v.w)));
        lmax = fmaxf(lmax, fmaxf(fmaxf(v.x, v.y), fmaxf(v.z, v.w)));
    }
    for (int i = (n4 << 2) + blockIdx.x * blockDim.x + threadIdx.x; i < n;
         i += gridDim.x * blockDim.x) {
        float v = pts[i];
        lmin = fminf(lmin, v);
        lmax = fmaxf(lmax, v);
    }
    __shared__ float smin[256], smax[256];
    smin[threadIdx.x] = lmin;
    smax[threadIdx.x] = lmax;
    __syncthreads();
    for (int s = 128; s > 0; s >>= 1) {
        if (threadIdx.x < (unsigned)s) {
            smin[threadIdx.x] = fminf(smin[threadIdx.x], smin[threadIdx.x + s]);
            smax[threadIdx.x] = fmaxf(smax[threadIdx.x], smax[threadIdx.x + s]);
        }
        __syncthreads();
    }
    if (threadIdx.x == 0) {
        atomicMin(&ws[0], enc_f32(smin[0]));
        atomicMax(&ws[1], enc_f32(smax[0]));
    }
}

// One thread per point: push point index onto its bin's linked list.
// 400k 4B atomics total (vs 25.6M in the per-channel atomic scatter).
__global__ void build_kernel(const float* __restrict__ pts,
                             const unsigned int* __restrict__ ws,
                             unsigned int* __restrict__ head,
                             unsigned int* __restrict__ next,
                             int ntot, int N) {
    int i = blockIdx.x * blockDim.x + threadIdx.x;
    if (i >= ntot) return;

    float pmin = dec_f32(ws[0]);
    float pmax = dec_f32(ws[1]);
    float denom = pmax - pmin + 1e-6f;

    float x = pts[i * 3 + 0];
    float y = pts[i * 3 + 1];
    float z = pts[i * 3 + 2];

    // Reference op order exactly: ((v - pmin) / denom) * 32, floor.
    // Values >= 0, so int-trunc == floor.
    int vx = (int)(((x - pmin) / denom) * 32.0f);
    int vy = (int)(((y - pmin) / denom) * 32.0f);
    int vz = (int)(((z - pmin) / denom) * 32.0f);
    vx = min(max(vx, 0), 31);
    vy = min(max(vy, 0), 31);
    vz = min(max(vz, 0), 31);

    int b = i / N;
    int bin = b * GRID3 + (vx << 10) + (vy << 5) + vz;

    unsigned int old = atomicExch(&head[bin], (unsigned int)i);
    next[i] = old;
}

// One wave per (batch,voxel) bin: chase list, fmax in registers, one plain
// 256B store. Empty bins store zeros => replaces the output memset.
__global__ __launch_bounds__(256)
void gather_kernel(const float* __restrict__ feat,
                   const unsigned int* __restrict__ head,
                   const unsigned int* __restrict__ next,
                   float* __restrict__ out, int nbins) {
    int bin = blockIdx.x * 4 + (threadIdx.x >> 6);
    int lane = threadIdx.x & 63;
    if (bin >= nbins) return;

    float acc = 0.0f;  // grid zero-init == implicit max with 0 (reference)
    unsigned int p = head[bin];
    while (p != 0xFFFFFFFFu) {
        float f = feat[(size_t)p * FDIM + lane];  // coalesced 256B gather
        unsigned int np = next[p];                // broadcast load (chain dep)
        acc = fmaxf(acc, f);
        p = np;
    }
    out[(size_t)bin * FDIM + lane] = acc;
}

// ---- Fallback (round-0 proven path) if workspace is too small ----
__global__ void scatter_kernel(const float* __restrict__ pts,
                               const float* __restrict__ feat,
                               const unsigned int* __restrict__ ws,
                               unsigned int* __restrict__ out,
                               int ntot, int N) {
    int lane = threadIdx.x & 63;
    int p = blockIdx.x * 4 + (threadIdx.x >> 6);
    if (p >= ntot) return;

    float pmin = dec_f32(ws[0]);
    float pmax = dec_f32(ws[1]);
    float denom = pmax - pmin + 1e-6f;

    float x = pts[p * 3 + 0];
    float y = pts[p * 3 + 1];
    float z = pts[p * 3 + 2];

    int vx = (int)floorf(((x - pmin) / denom) * 32.0f);
    int vy = (int)floorf(((y - pmin) / denom) * 32.0f);
    int vz = (int)floorf(((z - pmin) / denom) * 32.0f);
    vx = min(max(vx, 0), 31);
    vy = min(max(vy, 0), 31);
    vz = min(max(vz, 0), 31);
    int gidx = vx * 1024 + vy * 32 + vz;

    int b = p / N;
    float f = feat[(size_t)p * FDIM + lane];
    if (f > 0.0f) {
        unsigned int* addr = out + ((size_t)b * GRID3 + gidx) * FDIM + lane;
        atomicMax(addr, __float_as_uint(f));
    }
}

extern "C" void kernel_launch(void* const* d_in, const int* in_sizes, int n_in,
                              void* d_out, int out_size, void* d_ws, size_t ws_size,
                              hipStream_t stream) {
    const float* pts = (const float*)d_in[0];
    const float* feat = (const float*)d_in[1];
    unsigned int* ws = (unsigned int*)d_ws;

    int npts3 = in_sizes[0];            // B*N*3
    int ntot = npts3 / 3;               // B*N
    int B = out_size / (GRID3 * FDIM);
    int N = ntot / B;
    int nbins = B * GRID3;

    size_t need = 256 + (size_t)nbins * 4 + (size_t)ntot * 4;

    hipLaunchKernelGGL(init_ws_kernel, dim3(1), dim3(1), 0, stream, ws);
    hipLaunchKernelGGL(minmax_kernel, dim3(512), dim3(256), 0, stream,
                       pts, npts3, ws);

    if (ws_size >= need) {
        unsigned int* head = ws + 64;             // 256B-aligned region
        unsigned int* next = head + nbins;
        hipMemsetAsync(head, 0xFF, (size_t)nbins * 4, stream);
        hipLaunchKernelGGL(build_kernel, dim3((ntot + 255) / 256), dim3(256), 0,
                           stream, pts, ws, head, next, ntot, N);
        hipLaunchKernelGGL(gather_kernel, dim3((nbins + 3) / 4), dim3(256), 0,
                           stream, feat, head, next, (float*)d_out, nbins);
    } else {
        hipMemsetAsync(d_out, 0, (size_t)out_size * sizeof(float), stream);
        int blocks = (ntot + 3) / 4;
        hipLaunchKernelGGL(scatter_kernel, dim3(blocks), dim3(256), 0, stream,
                           pts, feat, ws, (unsigned int*)d_out, ntot, N);
    }
}

// Round 3
// 329.954 us; speedup vs baseline: 1.1677x; 1.0536x over previous
//
#include <hip/hip_runtime.h>

#define GRID3 32768  // 32^3
#define FDIM 64
#define CHUNK 512    // counts per scan chunk

// Order-preserving float<->uint encoding (monotonic: enc(a)<enc(b) iff a<b)
__device__ __forceinline__ unsigned int enc_f32(float f) {
    unsigned int u = __float_as_uint(f);
    return (u & 0x80000000u) ? ~u : (u | 0x80000000u);
}
__device__ __forceinline__ float dec_f32(unsigned int u) {
    u = (u & 0x80000000u) ? (u ^ 0x80000000u) : ~u;
    return __uint_as_float(u);
}

__device__ __forceinline__ int bin_of(float x, float y, float z,
                                      float pmin, float denom) {
    // Reference op order exactly: ((v - pmin) / denom) * 32, floor.
    // Values >= 0, so int-trunc == floor. (Clamp is a provable no-op but kept.)
    int vx = (int)(((x - pmin) / denom) * 32.0f);
    int vy = (int)(((y - pmin) / denom) * 32.0f);
    int vz = (int)(((z - pmin) / denom) * 32.0f);
    vx = min(max(vx, 0), 31);
    vy = min(max(vy, 0), 31);
    vz = min(max(vz, 0), 31);
    return (vx << 10) + (vy << 5) + vz;
}

__global__ void init_ws_kernel(unsigned int* ws) {
    ws[0] = 0xFFFFFFFFu;  // encoded min
    ws[1] = 0u;           // encoded max
}

__global__ void minmax_kernel(const float* __restrict__ pts, int n,
                              unsigned int* __restrict__ ws) {
    float lmin = INFINITY, lmax = -INFINITY;
    const float4* p4 = reinterpret_cast<const float4*>(pts);
    const int n4 = n >> 2;
    for (int i = blockIdx.x * blockDim.x + threadIdx.x; i < n4;
         i += gridDim.x * blockDim.x) {
        float4 v = p4[i];
        lmin = fminf(lmin, fminf(fminf(v.x, v.y), fminf(v.z, v.w)));
        lmax = fmaxf(lmax, fmaxf(fmaxf(v.x, v.y), fmaxf(v.z, v.w)));
    }
    for (int i = (n4 << 2) + blockIdx.x * blockDim.x + threadIdx.x; i < n;
         i += gridDim.x * blockDim.x) {
        float v = pts[i];
        lmin = fminf(lmin, v);
        lmax = fmaxf(lmax, v);
    }
    __shared__ float smin[256], smax[256];
    smin[threadIdx.x] = lmin;
    smax[threadIdx.x] = lmax;
    __syncthreads();
    for (int s = 128; s > 0; s >>= 1) {
        if (threadIdx.x < (unsigned)s) {
            smin[threadIdx.x] = fminf(smin[threadIdx.x], smin[threadIdx.x + s]);
            smax[threadIdx.x] = fmaxf(smax[threadIdx.x], smax[threadIdx.x + s]);
        }
        __syncthreads();
    }
    if (threadIdx.x == 0) {
        atomicMin(&ws[0], enc_f32(smin[0]));
        atomicMax(&ws[1], enc_f32(smax[0]));
    }
}

// Per-point histogram: 400k scattered 4B atomics over a 512KB L2-resident array.
__global__ void count_kernel(const float* __restrict__ pts,
                             const unsigned int* __restrict__ ws,
                             unsigned int* __restrict__ cnt,
                             int ntot, int N) {
    int i = blockIdx.x * blockDim.x + threadIdx.x;
    if (i >= ntot) return;
    float pmin = dec_f32(ws[0]);
    float denom = dec_f32(ws[1]) - pmin + 1e-6f;
    int bin = (i / N) * GRID3 +
              bin_of(pts[i * 3], pts[i * 3 + 1], pts[i * 3 + 2], pmin, denom);
    atomicAdd(&cnt[bin], 1u);
}

// Scan pass A: per-chunk sums (256 threads, 2 counts each).
__global__ __launch_bounds__(256)
void scanA_kernel(const unsigned int* __restrict__ cnt,
                  unsigned int* __restrict__ bsum, int nbins) {
    __shared__ unsigned int s[256];
    int base = blockIdx.x * CHUNK;
    int t = threadIdx.x;
    unsigned int a = (base + t < nbins) ? cnt[base + t] : 0u;
    unsigned int b = (base + t + 256 < nbins) ? cnt[base + t + 256] : 0u;
    s[t] = a + b;
    __syncthreads();
    for (int st = 128; st > 0; st >>= 1) {
        if (t < st) s[t] += s[t + st];
        __syncthreads();
    }
    if (t == 0) bsum[blockIdx.x] = s[0];
}

// Scan pass B: exclusive scan of chunk sums (single block, <=1024 chunks).
__global__ __launch_bounds__(1024)
void scanB_kernel(unsigned int* __restrict__ bsum, int nchunks) {
    __shared__ unsigned int s[1024];
    int t = threadIdx.x;
    unsigned int own = (t < nchunks) ? bsum[t] : 0u;
    s[t] = own;
    __syncthreads();
    for (int off = 1; off < 1024; off <<= 1) {
        unsigned int v = (t >= off) ? s[t - off] : 0u;
        __syncthreads();
        s[t] += v;
        __syncthreads();
    }
    if (t < nchunks) bsum[t] = s[t] - own;  // exclusive
}

// Scan pass C: within-chunk exclusive scan + chunk offset, in place.
__global__ __launch_bounds__(256)
void scanC_kernel(unsigned int* __restrict__ cnt,
                  const unsigned int* __restrict__ bsum, int nbins) {
    __shared__ unsigned int s[256];
    int t = threadIdx.x;
    int base = blockIdx.x * CHUNK;
    int i0 = base + 2 * t;
    unsigned int a = (i0 < nbins) ? cnt[i0] : 0u;
    unsigned int b = (i0 + 1 < nbins) ? cnt[i0 + 1] : 0u;
    unsigned int p = a + b;
    s[t] = p;
    __syncthreads();
    for (int off = 1; off < 256; off <<= 1) {
        unsigned int v = (t >= off) ? s[t - off] : 0u;
        __syncthreads();
        s[t] += v;
        __syncthreads();
    }
    unsigned int excl = s[t] - p + bsum[blockIdx.x];
    if (i0 < nbins) cnt[i0] = excl;
    if (i0 + 1 < nbins) cnt[i0 + 1] = excl + a;
}

// Fill: pos = cursor[bin]++ ; idx[pos] = point. After this pass,
// cursor[bin] == end offset of bin (== start offset of bin+1).
__global__ void fill_kernel(const float* __restrict__ pts,
                            const unsigned int* __restrict__ ws,
                            unsigned int* __restrict__ cursor,
                            unsigned int* __restrict__ idx,
                            int ntot, int N) {
    int i = blockIdx.x * blockDim.x + threadIdx.x;
    if (i >= ntot) return;
    float pmin = dec_f32(ws[0]);
    float denom = dec_f32(ws[1]) - pmin + 1e-6f;
    int bin = (i / N) * GRID3 +
              bin_of(pts[i * 3], pts[i * 3 + 1], pts[i * 3 + 2], pmin, denom);
    unsigned int pos = atomicAdd(&cursor[bin], 1u);
    idx[pos] = (unsigned int)i;
}

// Gather: one wave per bin. idx addresses are pure arithmetic in k (no
// dependent chain) -> loads pipeline. One plain 256B store per bin; empty
// bins store zeros (replaces output memset).
__global__ __launch_bounds__(256)
void gather_kernel(const float* __restrict__ feat,
                   const unsigned int* __restrict__ cursor,
                   const unsigned int* __restrict__ idx,
                   float* __restrict__ out, int nbins) {
    int bin = blockIdx.x * 4 + (threadIdx.x >> 6);
    int lane = threadIdx.x & 63;
    if (bin >= nbins) return;

    unsigned int s = bin ? cursor[bin - 1] : 0u;
    unsigned int e = cursor[bin];
    float acc = 0.0f;  // zeros-init grid == implicit max with 0 (reference)
    unsigned int k = s;
    for (; k + 4 <= e; k += 4) {
        unsigned int p0 = idx[k], p1 = idx[k + 1];
        unsigned int p2 = idx[k + 2], p3 = idx[k + 3];
        float f0 = feat[(size_t)p0 * FDIM + lane];
        float f1 = feat[(size_t)p1 * FDIM + lane];
        float f2 = feat[(size_t)p2 * FDIM + lane];
        float f3 = feat[(size_t)p3 * FDIM + lane];
        acc = fmaxf(acc, fmaxf(fmaxf(f0, f1), fmaxf(f2, f3)));
    }
    for (; k < e; ++k)
        acc = fmaxf(acc, feat[(size_t)idx[k] * FDIM + lane]);
    out[(size_t)bin * FDIM + lane] = acc;
}

// ---- Fallback (round-0 proven path) if workspace is too small ----
__global__ void scatter_kernel(const float* __restrict__ pts,
                               const float* __restrict__ feat,
                               const unsigned int* __restrict__ ws,
                               unsigned int* __restrict__ out,
                               int ntot, int N) {
    int lane = threadIdx.x & 63;
    int p = blockIdx.x * 4 + (threadIdx.x >> 6);
    if (p >= ntot) return;
    float pmin = dec_f32(ws[0]);
    float denom = dec_f32(ws[1]) - pmin + 1e-6f;
    int gidx = bin_of(pts[p * 3], pts[p * 3 + 1], pts[p * 3 + 2], pmin, denom);
    int b = p / N;
    float f = feat[(size_t)p * FDIM + lane];
    if (f > 0.0f) {
        unsigned int* addr = out + ((size_t)b * GRID3 + gidx) * FDIM + lane;
        atomicMax(addr, __float_as_uint(f));
    }
}

extern "C" void kernel_launch(void* const* d_in, const int* in_sizes, int n_in,
                              void* d_out, int out_size, void* d_ws, size_t ws_size,
                              hipStream_t stream) {
    const float* pts = (const float*)d_in[0];
    const float* feat = (const float*)d_in[1];
    unsigned int* ws = (unsigned int*)d_ws;

    int npts3 = in_sizes[0];            // B*N*3
    int ntot = npts3 / 3;               // B*N
    int B = out_size / (GRID3 * FDIM);
    int N = ntot / B;
    int nbins = B * GRID3;
    int nchunks = (nbins + CHUNK - 1) / CHUNK;

    // Workspace layout (4B units): [0..1] minmax | [64..] chunk sums (<=1024)
    // | cursor (nbins) | idx (ntot)
    unsigned int* bsum = ws + 64;
    unsigned int* cursor = bsum + 1024;
    unsigned int* idx = cursor + nbins;
    size_t need = (size_t)(64 + 1024 + nbins + ntot) * 4;

    hipLaunchKernelGGL(init_ws_kernel, dim3(1), dim3(1), 0, stream, ws);
    hipLaunchKernelGGL(minmax_kernel, dim3(512), dim3(256), 0, stream,
                       pts, npts3, ws);

    int pblocks = (ntot + 255) / 256;
    if (ws_size >= need && nchunks <= 1024) {
        hipMemsetAsync(cursor, 0, (size_t)nbins * 4, stream);
        hipLaunchKernelGGL(count_kernel, dim3(pblocks), dim3(256), 0, stream,
                           pts, ws, cursor, ntot, N);
        hipLaunchKernelGGL(scanA_kernel, dim3(nchunks), dim3(256), 0, stream,
                           cursor, bsum, nbins);
        hipLaunchKernelGGL(scanB_kernel, dim3(1), dim3(1024), 0, stream,
                           bsum, nchunks);
        hipLaunchKernelGGL(scanC_kernel, dim3(nchunks), dim3(256), 0, stream,
                           cursor, bsum, nbins);
        hipLaunchKernelGGL(fill_kernel, dim3(pblocks), dim3(256), 0, stream,
                           pts, ws, cursor, idx, ntot, N);
        hipLaunchKernelGGL(gather_kernel, dim3((nbins + 3) / 4), dim3(256), 0,
                           stream, feat, cursor, idx, (float*)d_out, nbins);
    } else {
        hipMemsetAsync(d_out, 0, (size_t)out_size * sizeof(float), stream);
        hipLaunchKernelGGL(scatter_kernel, dim3((ntot + 3) / 4), dim3(256), 0,
                           stream, pts, feat, ws, (unsigned int*)d_out, ntot, N);
    }
}

// Round 4
// 290.458 us; speedup vs baseline: 1.3265x; 1.1360x over previous
//
#include <hip/hip_runtime.h>

#define GRID3 32768  // 32^3
#define FDIM 64
#define CHUNK 512    // counts per scan chunk

// Order-preserving float<->uint encoding (monotonic: enc(a)<enc(b) iff a<b)
__device__ __forceinline__ unsigned int enc_f32(float f) {
    unsigned int u = __float_as_uint(f);
    return (u & 0x80000000u) ? ~u : (u | 0x80000000u);
}
__device__ __forceinline__ float dec_f32(unsigned int u) {
    u = (u & 0x80000000u) ? (u ^ 0x80000000u) : ~u;
    return __uint_as_float(u);
}

__device__ __forceinline__ int bin_of(float x, float y, float z,
                                      float pmin, float denom) {
    // Reference op order exactly: ((v - pmin) / denom) * 32, floor.
    // Values >= 0, so int-trunc == floor. (Clamp is a provable no-op but kept.)
    int vx = (int)(((x - pmin) / denom) * 32.0f);
    int vy = (int)(((y - pmin) / denom) * 32.0f);
    int vz = (int)(((z - pmin) / denom) * 32.0f);
    vx = min(max(vx, 0), 31);
    vy = min(max(vy, 0), 31);
    vz = min(max(vz, 0), 31);
    return (vx << 10) + (vy << 5) + vz;
}

__global__ void init_ws_kernel(unsigned int* ws) {
    ws[0] = 0xFFFFFFFFu;  // encoded min
    ws[1] = 0u;           // encoded max
}

__global__ void minmax_kernel(const float* __restrict__ pts, int n,
                              unsigned int* __restrict__ ws) {
    float lmin = INFINITY, lmax = -INFINITY;
    const float4* p4 = reinterpret_cast<const float4*>(pts);
    const int n4 = n >> 2;
    for (int i = blockIdx.x * blockDim.x + threadIdx.x; i < n4;
         i += gridDim.x * blockDim.x) {
        float4 v = p4[i];
        lmin = fminf(lmin, fminf(fminf(v.x, v.y), fminf(v.z, v.w)));
        lmax = fmaxf(lmax, fmaxf(fmaxf(v.x, v.y), fmaxf(v.z, v.w)));
    }
    for (int i = (n4 << 2) + blockIdx.x * blockDim.x + threadIdx.x; i < n;
         i += gridDim.x * blockDim.x) {
        float v = pts[i];
        lmin = fminf(lmin, v);
        lmax = fmaxf(lmax, v);
    }
    __shared__ float smin[256], smax[256];
    smin[threadIdx.x] = lmin;
    smax[threadIdx.x] = lmax;
    __syncthreads();
    for (int s = 128; s > 0; s >>= 1) {
        if (threadIdx.x < (unsigned)s) {
            smin[threadIdx.x] = fminf(smin[threadIdx.x], smin[threadIdx.x + s]);
            smax[threadIdx.x] = fmaxf(smax[threadIdx.x], smax[threadIdx.x + s]);
        }
        __syncthreads();
    }
    if (threadIdx.x == 0) {
        atomicMin(&ws[0], enc_f32(smin[0]));
        atomicMax(&ws[1], enc_f32(smax[0]));
    }
}

// Per-point histogram: 400k scattered 4B atomics over a 512KB L2-resident array.
__global__ void count_kernel(const float* __restrict__ pts,
                             const unsigned int* __restrict__ ws,
                             unsigned int* __restrict__ cnt,
                             int ntot, int N) {
    int i = blockIdx.x * blockDim.x + threadIdx.x;
    if (i >= ntot) return;
    float pmin = dec_f32(ws[0]);
    float denom = dec_f32(ws[1]) - pmin + 1e-6f;
    int bin = (i / N) * GRID3 +
              bin_of(pts[i * 3], pts[i * 3 + 1], pts[i * 3 + 2], pmin, denom);
    atomicAdd(&cnt[bin], 1u);
}

// Scan pass A: per-chunk sums (256 threads, 2 counts each).
__global__ __launch_bounds__(256)
void scanA_kernel(const unsigned int* __restrict__ cnt,
                  unsigned int* __restrict__ bsum, int nbins) {
    __shared__ unsigned int s[256];
    int base = blockIdx.x * CHUNK;
    int t = threadIdx.x;
    unsigned int a = (base + t < nbins) ? cnt[base + t] : 0u;
    unsigned int b = (base + t + 256 < nbins) ? cnt[base + t + 256] : 0u;
    s[t] = a + b;
    __syncthreads();
    for (int st = 128; st > 0; st >>= 1) {
        if (t < st) s[t] += s[t + st];
        __syncthreads();
    }
    if (t == 0) bsum[blockIdx.x] = s[0];
}

// Scan pass B: exclusive scan of chunk sums (single block, <=1024 chunks).
__global__ __launch_bounds__(1024)
void scanB_kernel(unsigned int* __restrict__ bsum, int nchunks) {
    __shared__ unsigned int s[1024];
    int t = threadIdx.x;
    unsigned int own = (t < nchunks) ? bsum[t] : 0u;
    s[t] = own;
    __syncthreads();
    for (int off = 1; off < 1024; off <<= 1) {
        unsigned int v = (t >= off) ? s[t - off] : 0u;
        __syncthreads();
        s[t] += v;
        __syncthreads();
    }
    if (t < nchunks) bsum[t] = s[t] - own;  // exclusive
}

// Scan pass C: within-chunk exclusive scan + chunk offset, in place.
__global__ __launch_bounds__(256)
void scanC_kernel(unsigned int* __restrict__ cnt,
                  const unsigned int* __restrict__ bsum, int nbins) {
    __shared__ unsigned int s[256];
    int t = threadIdx.x;
    int base = blockIdx.x * CHUNK;
    int i0 = base + 2 * t;
    unsigned int a = (i0 < nbins) ? cnt[i0] : 0u;
    unsigned int b = (i0 + 1 < nbins) ? cnt[i0 + 1] : 0u;
    unsigned int p = a + b;
    s[t] = p;
    __syncthreads();
    for (int off = 1; off < 256; off <<= 1) {
        unsigned int v = (t >= off) ? s[t - off] : 0u;
        __syncthreads();
        s[t] += v;
        __syncthreads();
    }
    unsigned int excl = s[t] - p + bsum[blockIdx.x];
    if (i0 < nbins) cnt[i0] = excl;
    if (i0 + 1 < nbins) cnt[i0 + 1] = excl + a;
}

// Fill: pos = cursor[bin]++ ; idx[pos] = point. After this pass,
// cursor[bin] == end offset of bin (== start offset of bin+1).
__global__ void fill_kernel(const float* __restrict__ pts,
                            const unsigned int* __restrict__ ws,
                            unsigned int* __restrict__ cursor,
                            unsigned int* __restrict__ idx,
                            int ntot, int N) {
    int i = blockIdx.x * blockDim.x + threadIdx.x;
    if (i >= ntot) return;
    float pmin = dec_f32(ws[0]);
    float denom = dec_f32(ws[1]) - pmin + 1e-6f;
    int bin = (i / N) * GRID3 +
              bin_of(pts[i * 3], pts[i * 3 + 1], pts[i * 3 + 2], pmin, denom);
    unsigned int pos = atomicAdd(&cursor[bin], 1u);
    idx[pos] = (unsigned int)i;
}

// Gather: one wave per bin. Unroll-16 => 16 independent 256B feat loads in
// flight per wave (latency-bound fix: R3's unroll-4 gave only 1KB/wave MLP).
// All array indexing is compile-time after unroll => stays in VGPRs.
// One plain 256B store per bin; empty bins store zeros (replaces memset).
__global__ __launch_bounds__(256)
void gather_kernel(const float* __restrict__ feat,
                   const unsigned int* __restrict__ cursor,
                   const unsigned int* __restrict__ idx,
                   float* __restrict__ out, int nbins) {
    int bin = blockIdx.x * 4 + (threadIdx.x >> 6);
    int lane = threadIdx.x & 63;
    if (bin >= nbins) return;

    unsigned int s = bin ? cursor[bin - 1] : 0u;
    unsigned int e = cursor[bin];
    const float* fl = feat + lane;
    float acc = 0.0f;  // zeros-init grid == implicit max with 0 (reference)
    unsigned int k = s;

    for (; k + 16 <= e; k += 16) {
        unsigned int p[16];
#pragma unroll
        for (int j = 0; j < 16; ++j) p[j] = idx[k + j];
        float f[16];
#pragma unroll
        for (int j = 0; j < 16; ++j) f[j] = fl[(size_t)p[j] * FDIM];
        float m = f[0];
#pragma unroll
        for (int j = 1; j < 16; ++j) m = fmaxf(m, f[j]);
        acc = fmaxf(acc, m);
    }
    for (; k + 4 <= e; k += 4) {
        unsigned int p0 = idx[k], p1 = idx[k + 1];
        unsigned int p2 = idx[k + 2], p3 = idx[k + 3];
        float f0 = fl[(size_t)p0 * FDIM];
        float f1 = fl[(size_t)p1 * FDIM];
        float f2 = fl[(size_t)p2 * FDIM];
        float f3 = fl[(size_t)p3 * FDIM];
        acc = fmaxf(acc, fmaxf(fmaxf(f0, f1), fmaxf(f2, f3)));
    }
    for (; k < e; ++k)
        acc = fmaxf(acc, fl[(size_t)idx[k] * FDIM]);
    out[(size_t)bin * FDIM + lane] = acc;
}

// ---- Fallback (round-0 proven path) if workspace is too small ----
__global__ void scatter_kernel(const float* __restrict__ pts,
                               const float* __restrict__ feat,
                               const unsigned int* __restrict__ ws,
                               unsigned int* __restrict__ out,
                               int ntot, int N) {
    int lane = threadIdx.x & 63;
    int p = blockIdx.x * 4 + (threadIdx.x >> 6);
    if (p >= ntot) return;
    float pmin = dec_f32(ws[0]);
    float denom = dec_f32(ws[1]) - pmin + 1e-6f;
    int gidx = bin_of(pts[p * 3], pts[p * 3 + 1], pts[p * 3 + 2], pmin, denom);
    int b = p / N;
    float f = feat[(size_t)p * FDIM + lane];
    if (f > 0.0f) {
        unsigned int* addr = out + ((size_t)b * GRID3 + gidx) * FDIM + lane;
        atomicMax(addr, __float_as_uint(f));
    }
}

extern "C" void kernel_launch(void* const* d_in, const int* in_sizes, int n_in,
                              void* d_out, int out_size, void* d_ws, size_t ws_size,
                              hipStream_t stream) {
    const float* pts = (const float*)d_in[0];
    const float* feat = (const float*)d_in[1];
    unsigned int* ws = (unsigned int*)d_ws;

    int npts3 = in_sizes[0];            // B*N*3
    int ntot = npts3 / 3;               // B*N
    int B = out_size / (GRID3 * FDIM);
    int N = ntot / B;
    int nbins = B * GRID3;
    int nchunks = (nbins + CHUNK - 1) / CHUNK;

    // Workspace layout (4B units): [0..1] minmax | [64..] chunk sums (<=1024)
    // | cursor (nbins) | idx (ntot)
    unsigned int* bsum = ws + 64;
    unsigned int* cursor = bsum + 1024;
    unsigned int* idx = cursor + nbins;
    size_t need = (size_t)(64 + 1024 + nbins + ntot) * 4;

    hipLaunchKernelGGL(init_ws_kernel, dim3(1), dim3(1), 0, stream, ws);
    hipLaunchKernelGGL(minmax_kernel, dim3(512), dim3(256), 0, stream,
                       pts, npts3, ws);

    int pblocks = (ntot + 255) / 256;
    if (ws_size >= need && nchunks <= 1024) {
        hipMemsetAsync(cursor, 0, (size_t)nbins * 4, stream);
        hipLaunchKernelGGL(count_kernel, dim3(pblocks), dim3(256), 0, stream,
                           pts, ws, cursor, ntot, N);
        hipLaunchKernelGGL(scanA_kernel, dim3(nchunks), dim3(256), 0, stream,
                           cursor, bsum, nbins);
        hipLaunchKernelGGL(scanB_kernel, dim3(1), dim3(1024), 0, stream,
                           bsum, nchunks);
        hipLaunchKernelGGL(scanC_kernel, dim3(nchunks), dim3(256), 0, stream,
                           cursor, bsum, nbins);
        hipLaunchKernelGGL(fill_kernel, dim3(pblocks), dim3(256), 0, stream,
                           pts, ws, cursor, idx, ntot, N);
        hipLaunchKernelGGL(gather_kernel, dim3((nbins + 3) / 4), dim3(256), 0,
                           stream, feat, cursor, idx, (float*)d_out, nbins);
    } else {
        hipMemsetAsync(d_out, 0, (size_t)out_size * sizeof(float), stream);
        hipLaunchKernelGGL(scatter_kernel, dim3((ntot + 3) / 4), dim3(256), 0,
                           stream, pts, feat, ws, (unsigned int*)d_out, ntot, N);
    }
}